// Round 13
// baseline (127.431 us; speedup 1.0000x reference)
//
#include <hip/hip_runtime.h>
#include <hip/hip_bf16.h>
#include <math.h>

#define RS2f 0.70710678118654752f

typedef __attribute__((ext_vector_type(8))) short bf16x8;
typedef __attribute__((ext_vector_type(4))) float f32x4;
typedef __attribute__((ext_vector_type(2))) float f32x2;   // <2 x float> -> v_pk_* on gfx950

__device__ __forceinline__ float bf2f(unsigned short h) {
    return __uint_as_float(((unsigned)h) << 16);
}
// HW packed fp32x2 -> bf16x2 (v_cvt_pk_bf16_f32 on gfx950, RNE)
__device__ __forceinline__ ushort2 pk2(float a, float b) {
    union { __hip_bfloat162 h; ushort2 s; } u;
    u.h = __float22bfloat162_rn(make_float2(a, b));
    return u.s;
}

// ==================== rotation matrices ====================
struct CMat { float m00r,m00i,m01r,m01i,m10r,m10i,m11r,m11i; };

__device__ __forceinline__ CMat mk_rot(const float* __restrict__ qp, int l, int w) {
    const float* g = qp + (l * 12 + w) * 3;
    float phi = g[0], th = g[1], om = g[2];
    float st, ct, sa, ca, sb, cb;
    sincosf(0.5f * th, &st, &ct);
    sincosf(0.5f * (phi + om), &sa, &ca);
    sincosf(0.5f * (phi - om), &sb, &cb);
    CMat M;
    M.m00r =  ct * ca; M.m00i = -ct * sa;
    M.m01r = -st * cb; M.m01i = -st * sb;
    M.m10r =  st * cb; M.m10i = -st * sb;
    M.m11r =  ct * ca; M.m11i =  ct * sa;
    return M;
}

// ==================================================================
// GEMM (unchanged, verified since R6): 128x128 tile, SK=16, grid 512.
// ==================================================================
__global__ __launch_bounds__(512) void gemm_fused(const float* __restrict__ A,  // 1024x2048
                                                  const float* __restrict__ B,  // 512x2048
                                                  float* __restrict__ P,
                                                  const float* __restrict__ qp,
                                                  CMat* __restrict__ cmg) {
    __shared__ short As[128 * 136];      // 34816 B
    __shared__ short Bs[128 * 136];      // 34816 B
    const int tid = threadIdx.x, lane = tid & 63, wv = tid >> 6;   // wv 0..7
    const int quad = lane >> 4, mrow = lane & 15;
    const int bid = blockIdx.x;
    if (bid == 0 && tid < 24) cmg[tid] = mk_rot(qp, tid / 12, tid % 12);
    const int zt  = bid & 15;                      // K-slice 0..15
    const int idx = bid >> 4;                      // 0..31
    const int mt  = idx & 7, nt = idx >> 3;        // 8 m-tiles x 4 n-tiles
    const int m0 = mt * 128, n0 = nt * 128;
    const int kb = zt * 128;                       // fp32 K base (2048/16)
    const int srow = tid >> 2;                     // 0..127
    const int sc = (tid & 3) * 16;                 // fp32 col group

    f32x4 acc[8];
    #pragma unroll
    for (int j = 0; j < 8; ++j) acc[j] = (f32x4){0.f, 0.f, 0.f, 0.f};

    const float* Arow = A + (size_t)(m0 + srow) * 2048 + kb + sc;
    const float* Brow = B + (size_t)(n0 + srow) * 2048 + kb + sc;

    float4 av[4], bv[4];
    #pragma unroll
    for (int i = 0; i < 4; ++i) { av[i] = *(const float4*)(Arow + 4*i);
                                  bv[i] = *(const float4*)(Brow + 4*i); }

    for (int ch = 0; ch < 2; ++ch) {               // 2 x BK=64 fp32 = 128
        __syncthreads();
        #pragma unroll
        for (int i = 0; i < 4; ++i) {
            ushort2 h0 = pk2(av[i].x, av[i].y);
            ushort2 h1 = pk2(av[i].z, av[i].w);
            ushort2 l0 = pk2(av[i].x - bf2f(h0.x), av[i].y - bf2f(h0.y));
            ushort2 l1 = pk2(av[i].z - bf2f(h1.x), av[i].w - bf2f(h1.y));
            *(ushort4*)&As[srow * 136 + sc + 4*i]      = make_ushort4(h0.x, h0.y, h1.x, h1.y);
            *(ushort4*)&As[srow * 136 + 64 + sc + 4*i] = make_ushort4(l0.x, l0.y, l1.x, l1.y);
            h0 = pk2(bv[i].x, bv[i].y);
            h1 = pk2(bv[i].z, bv[i].w);
            l0 = pk2(bv[i].x - bf2f(h0.x), bv[i].y - bf2f(h0.y));
            l1 = pk2(bv[i].z - bf2f(h1.x), bv[i].w - bf2f(h1.y));
            *(ushort4*)&Bs[srow * 136 + sc + 4*i]      = make_ushort4(h0.x, h0.y, h1.x, h1.y);
            *(ushort4*)&Bs[srow * 136 + 64 + sc + 4*i] = make_ushort4(l0.x, l0.y, l1.x, l1.y);
        }
        __syncthreads();
        if (ch + 1 < 2) {
            const int o = 64;
            #pragma unroll
            for (int i = 0; i < 4; ++i) { av[i] = *(const float4*)(Arow + o + 4*i);
                                          bv[i] = *(const float4*)(Brow + o + 4*i); }
        }
        #pragma unroll
        for (int s = 0; s < 4; ++s) {              // K-segments: 2 hi, 2 lo
            const int off = s * 32 + quad * 8;
            bf16x8 af = *(const bf16x8*)&As[(wv * 16 + mrow) * 136 + off];
            #pragma unroll
            for (int j = 0; j < 8; ++j) {
                bf16x8 bf = *(const bf16x8*)&Bs[(j * 16 + mrow) * 136 + off];
                acc[j] = __builtin_amdgcn_mfma_f32_16x16x32_bf16(af, bf, acc[j], 0, 0, 0);
            }
        }
    }
    // C/D layout: col = lane&15, row = quad*4 + r
    float* Pz = P + (size_t)zt * 524288;
    #pragma unroll
    for (int j = 0; j < 8; ++j)
        #pragma unroll
        for (int r = 0; r < 4; ++r)
            Pz[(m0 + wv * 16 + quad * 4 + r) * 512 + n0 + j * 16 + mrow] = acc[j][r];
}

// ==================================================================
// Fallback fp32 GEMM (tiny ws): raw product to P; circuit adds bias.
// ==================================================================
__global__ __launch_bounds__(256) void gemm_f32(const float* __restrict__ A,
                                                const float* __restrict__ W,
                                                float* __restrict__ C,
                                                const float* __restrict__ qp,
                                                CMat* __restrict__ cmg) {
    __shared__ float Asf[64][33];
    __shared__ float Bsf[32][33];
    const int tid = threadIdx.x;
    if (blockIdx.x == 0 && blockIdx.y == 0 && tid < 24)
        cmg[tid] = mk_rot(qp, tid / 12, tid % 12);
    const int m0 = blockIdx.x * 64;
    const int n0 = blockIdx.y * 32;
    const int tm = tid >> 4, tn = tid & 15;
    float acc[4][2] = {};
    for (int k0 = 0; k0 < 2048; k0 += 32) {
        #pragma unroll
        for (int i = 0; i < 8; ++i) {
            int idx = tid + i * 256;
            Asf[idx >> 5][idx & 31] = A[(m0 + (idx >> 5)) * 2048 + k0 + (idx & 31)];
        }
        #pragma unroll
        for (int i = 0; i < 4; ++i) {
            int idx = tid + i * 256;
            Bsf[idx >> 5][idx & 31] = W[(n0 + (idx >> 5)) * 2048 + k0 + (idx & 31)];
        }
        __syncthreads();
        #pragma unroll
        for (int kk = 0; kk < 32; ++kk) {
            float a0 = Asf[tm*4+0][kk], a1 = Asf[tm*4+1][kk];
            float a2 = Asf[tm*4+2][kk], a3 = Asf[tm*4+3][kk];
            float b0 = Bsf[tn*2+0][kk], b1 = Bsf[tn*2+1][kk];
            acc[0][0] += a0*b0; acc[0][1] += a0*b1;
            acc[1][0] += a1*b0; acc[1][1] += a1*b1;
            acc[2][0] += a2*b0; acc[2][1] += a2*b1;
            acc[3][0] += a3*b0; acc[3][1] += a3*b1;
        }
        __syncthreads();
    }
    #pragma unroll
    for (int r = 0; r < 4; ++r)
        #pragma unroll
        for (int c = 0; c < 2; ++c)
            C[(m0 + tm*4 + r) * 512 + n0 + tn*2 + c] = acc[r][c];
}

// ==================== circuit helpers ====================
// R27 = verified R24 + ONLY the init-fold (rot0@l0 into init, zero
// extra register pressure). The cnot110_rot0 fusion is DROPPED --
// R12 showed it raised VGPR 48->68, occupancy 29.6->22.9%, net -3.4us.
// 9 exchanges. Plain launch_bounds(256).
template<int W> struct WI {
    static constexpr int kind = (W == 0 || W == 7) ? 2 : ((W >= 1 && W <= 6) ? 1 : 0);
    static constexpr int eb   = (W >= 8) ? (11 - W) : 0;
    static constexpr int lm   = (W >= 1 && W <= 6) ? (1 << (6 - W)) : 0;
    static constexpr int vm   = (W == 0) ? 2 : ((W == 7) ? 1 : 0);
};

// xor-shuffle: DPP for masks 1,2,8 (exact lane permutations, all lanes
// active at every callsite); ds path otherwise.
template<int M>
__device__ __forceinline__ float xshfl(float v) {
    if constexpr (M == 1) {        // quad_perm [1,0,3,2]
        return __int_as_float(__builtin_amdgcn_update_dpp(
            __float_as_int(v), __float_as_int(v), 177, 0xf, 0xf, false));
    } else if constexpr (M == 2) { // quad_perm [2,3,0,1]
        return __int_as_float(__builtin_amdgcn_update_dpp(
            __float_as_int(v), __float_as_int(v), 78, 0xf, 0xf, false));
    } else if constexpr (M == 8) { // row_ror:8 (16-lane row; +8 mod 16 == xor 8)
        return __int_as_float(__builtin_amdgcn_update_dpp(
            __float_as_int(v), __float_as_int(v), 0x128, 0xf, 0xf, false));
    } else {
        return __shfl_xor(v, M, 64);
    }
}

__device__ __forceinline__ float getv(const f32x2 a[8], int e) {
    return (e & 1) ? a[e >> 1].y : a[e >> 1].x;
}
__device__ __forceinline__ void setv(f32x2 a[8], int e, float v) {
    if (e & 1) a[e >> 1].y = v; else a[e >> 1].x = v;
}

__device__ __forceinline__ void exch_put(float* xbuf, int slot,
                                         const f32x2 vr[8], const f32x2 vi[8]) {
    __syncthreads();
    float4* p = (float4*)xbuf;
    #pragma unroll
    for (int j = 0; j < 8; ++j)
        p[(j << 8) + slot] = make_float4(vr[j].x, vi[j].x, vr[j].y, vi[j].y);
    __syncthreads();
}

__device__ __forceinline__ void shfl_perm(f32x2 vr[8], f32x2 vi[8], int src) {
    #pragma unroll
    for (int p = 0; p < 8; ++p) {
        vr[p].x = __shfl(vr[p].x, src, 64); vr[p].y = __shfl(vr[p].y, src, 64);
        vi[p].x = __shfl(vi[p].x, src, 64); vi[p].y = __shfl(vi[p].y, src, 64);
    }
}

template<int EB>
__device__ __forceinline__ void rot_local(f32x2 vr[8], f32x2 vi[8], const CMat& M) {
    if constexpr (EB == 0) {
        #pragma unroll
        for (int p = 0; p < 8; ++p) {
            float x0r = vr[p].x, x0i = vi[p].x, x1r = vr[p].y, x1i = vi[p].y;
            vr[p].x = M.m00r*x0r - M.m00i*x0i + M.m01r*x1r - M.m01i*x1i;
            vi[p].x = M.m00r*x0i + M.m00i*x0r + M.m01r*x1i + M.m01i*x1r;
            vr[p].y = M.m10r*x0r - M.m10i*x0i + M.m11r*x1r - M.m11i*x1i;
            vi[p].y = M.m10r*x0i + M.m10i*x0r + M.m11r*x1i + M.m11i*x1r;
        }
    } else {
        constexpr int pb = 1 << (EB - 1);
        #pragma unroll
        for (int p = 0; p < 8; ++p) if (!(p & pb)) {
            const int p1 = p | pb;
            f32x2 x0r = vr[p], x0i = vi[p], x1r = vr[p1], x1i = vi[p1];
            vr[p]  = M.m00r*x0r - M.m00i*x0i + M.m01r*x1r - M.m01i*x1i;
            vi[p]  = M.m00r*x0i + M.m00i*x0r + M.m01r*x1i + M.m01i*x1r;
            vr[p1] = M.m10r*x0r - M.m10i*x0i + M.m11r*x1r - M.m11i*x1i;
            vi[p1] = M.m10r*x0i + M.m10i*x0r + M.m11r*x1i + M.m11i*x1r;
        }
    }
}

template<int LM>
__device__ __forceinline__ void rot_lane(f32x2 vr[8], f32x2 vi[8], int lane, const CMat& M) {
    const bool hi = lane & LM;
    const float Ar = hi ? M.m11r : M.m00r, Ai = hi ? M.m11i : M.m00i;
    const float Br = hi ? M.m10r : M.m01r, Bi = hi ? M.m10i : M.m01i;
    #pragma unroll
    for (int p = 0; p < 8; ++p) {
        f32x2 p_r = { xshfl<LM>(vr[p].x), xshfl<LM>(vr[p].y) };
        f32x2 p_i = { xshfl<LM>(vi[p].x), xshfl<LM>(vi[p].y) };
        f32x2 o_r = vr[p], o_i = vi[p];
        vr[p] = Ar*o_r - Ai*o_i + Br*p_r - Bi*p_i;
        vi[p] = Ar*o_i + Ai*o_r + Br*p_i + Bi*p_r;
    }
}

template<int VM>
__device__ __forceinline__ void rot_wave(f32x2 vr[8], f32x2 vi[8], float* xbuf,
                                         int waveId, int lane, const CMat& M) {
    exch_put(xbuf, (waveId << 6) + lane, vr, vi);
    const float4* p = (const float4*)xbuf;
    const int ps = ((waveId ^ VM) << 6) + lane;
    const bool hi = waveId & VM;
    const float Ar = hi ? M.m11r : M.m00r, Ai = hi ? M.m11i : M.m00i;
    const float Br = hi ? M.m10r : M.m01r, Bi = hi ? M.m10i : M.m01i;
    #pragma unroll
    for (int j = 0; j < 8; ++j) {
        float4 q = p[(j << 8) + ps];
        f32x2 q_r = {q.x, q.z}, q_i = {q.y, q.w};
        f32x2 o_r = vr[j], o_i = vi[j];
        vr[j] = Ar*o_r - Ai*o_i + Br*q_r - Bi*q_i;
        vi[j] = Ar*o_i + Ai*o_r + Br*q_i + Bi*q_r;
    }
}

template<int W>
__device__ __forceinline__ void rot_wire(f32x2 vr[8], f32x2 vi[8], float* xbuf,
                                         int waveId, int lane, const CMat& M) {
    if constexpr (WI<W>::kind == 0)      rot_local<WI<W>::eb>(vr, vi, M);
    else if constexpr (WI<W>::kind == 1) rot_lane<WI<W>::lm>(vr, vi, lane, M);
    else                                 rot_wave<WI<W>::vm>(vr, vi, xbuf, waveId, lane, M);
}

template<int C, int T>
__device__ __forceinline__ void cnot(f32x2 vr[8], f32x2 vi[8], float* xbuf,
                                     int waveId, int lane) {
    constexpr int ck = WI<C>::kind, tk = WI<T>::kind;
    if constexpr (ck == 0 && tk == 0) {
        constexpr int cb = 1 << WI<C>::eb, tb = 1 << WI<T>::eb;
        #pragma unroll
        for (int e = 0; e < 16; ++e) if ((e & cb) && !(e & tb)) {
            const int e1 = e | tb;
            float t = getv(vr, e); setv(vr, e, getv(vr, e1)); setv(vr, e1, t);
            t = getv(vi, e); setv(vi, e, getv(vi, e1)); setv(vi, e1, t);
        }
    } else if constexpr (ck == 0 && tk == 1) {
        constexpr int cb = 1 << WI<C>::eb, tm = WI<T>::lm;
        #pragma unroll
        for (int e = 0; e < 16; ++e) if (e & cb) {
            setv(vr, e, xshfl<tm>(getv(vr, e)));
            setv(vi, e, xshfl<tm>(getv(vi, e)));
        }
    } else if constexpr (ck == 0 && tk == 2) {
        constexpr int cb = 1 << WI<C>::eb, vm = WI<T>::vm;
        exch_put(xbuf, (waveId << 6) + lane, vr, vi);
        const float4* p = (const float4*)xbuf;
        const int ps = ((waveId ^ vm) << 6) + lane;
        #pragma unroll
        for (int j = 0; j < 8; ++j) {
            if ((((2*j) & cb) != 0) || (((2*j+1) & cb) != 0)) {
                float4 q = p[(j << 8) + ps];
                if (((2*j) & cb) != 0)   { vr[j].x = q.x; vi[j].x = q.y; }
                if (((2*j+1) & cb) != 0) { vr[j].y = q.z; vi[j].y = q.w; }
            }
        }
    } else if constexpr (ck == 1 && tk == 0) {
        constexpr int cm = WI<C>::lm, tb = 1 << WI<T>::eb;
        const bool cc = lane & cm;
        #pragma unroll
        for (int e = 0; e < 16; ++e) if (!(e & tb)) {
            const int e1 = e | tb;
            float a = getv(vr, e), bb = getv(vr, e1);
            setv(vr, e, cc ? bb : a); setv(vr, e1, cc ? a : bb);
            a = getv(vi, e); bb = getv(vi, e1);
            setv(vi, e, cc ? bb : a); setv(vi, e1, cc ? a : bb);
        }
    } else if constexpr (ck == 1 && tk == 1) {
        constexpr int cm = WI<C>::lm, tm = WI<T>::lm;
        const int src = (lane & cm) ? (lane ^ tm) : lane;
        shfl_perm(vr, vi, src);
    } else if constexpr (ck == 1 && tk == 2) {
        constexpr int cm = WI<C>::lm, vm = WI<T>::vm;
        exch_put(xbuf, (waveId << 6) + lane, vr, vi);
        const float4* p = (const float4*)xbuf;
        const int ps = ((waveId ^ vm) << 6) + lane;
        const bool take = lane & cm;
        #pragma unroll
        for (int j = 0; j < 8; ++j) {
            float4 q = p[(j << 8) + ps];
            vr[j].x = take ? q.x : vr[j].x;   vi[j].x = take ? q.y : vi[j].x;
            vr[j].y = take ? q.z : vr[j].y;   vi[j].y = take ? q.w : vi[j].y;
        }
    } else if constexpr (ck == 2 && tk == 0) {
        constexpr int vm = WI<C>::vm, tb = 1 << WI<T>::eb;
        if (waveId & vm) {
            #pragma unroll
            for (int e = 0; e < 16; ++e) if (!(e & tb)) {
                const int e1 = e | tb;
                float t = getv(vr, e); setv(vr, e, getv(vr, e1)); setv(vr, e1, t);
                t = getv(vi, e); setv(vi, e, getv(vi, e1)); setv(vi, e1, t);
            }
        }
    } else {
        constexpr int vm = WI<C>::vm, tm = WI<T>::lm;
        if (waveId & vm) {
            #pragma unroll
            for (int e = 0; e < 16; ++e) {
                setv(vr, e, __shfl_xor(getv(vr, e), tm, 64));
                setv(vi, e, __shfl_xor(getv(vi, e), tm, 64));
            }
        }
    }
}

template<int W>
__device__ __forceinline__ void h_wire(f32x2 vr[8], f32x2 vi[8], float* xbuf,
                                       int waveId, int lane) {
    if constexpr (WI<W>::kind == 0) {
        if constexpr (WI<W>::eb == 0) {
            #pragma unroll
            for (int p = 0; p < 8; ++p) {
                float x0 = vr[p].x, x1 = vr[p].y;
                vr[p].x = (x0 + x1) * RS2f; vr[p].y = (x0 - x1) * RS2f;
                x0 = vi[p].x; x1 = vi[p].y;
                vi[p].x = (x0 + x1) * RS2f; vi[p].y = (x0 - x1) * RS2f;
            }
        } else {
            constexpr int pb = 1 << (WI<W>::eb - 1);
            #pragma unroll
            for (int p = 0; p < 8; ++p) if (!(p & pb)) {
                const int p1 = p | pb;
                f32x2 a = vr[p], b = vr[p1];
                vr[p] = (a + b) * RS2f; vr[p1] = (a - b) * RS2f;
                a = vi[p]; b = vi[p1];
                vi[p] = (a + b) * RS2f; vi[p1] = (a - b) * RS2f;
            }
        }
    } else if constexpr (WI<W>::kind == 1) {
        constexpr int m = WI<W>::lm;
        const float sgn = (lane & m) ? -RS2f : RS2f;
        #pragma unroll
        for (int p = 0; p < 8; ++p) {
            f32x2 p_r = { xshfl<m>(vr[p].x), xshfl<m>(vr[p].y) };
            f32x2 p_i = { xshfl<m>(vi[p].x), xshfl<m>(vi[p].y) };
            vr[p] = p_r * RS2f + vr[p] * sgn;
            vi[p] = p_i * RS2f + vi[p] * sgn;
        }
    } else {
        constexpr int vm = WI<W>::vm;
        exch_put(xbuf, (waveId << 6) + lane, vr, vi);
        const float4* p = (const float4*)xbuf;
        const int ps = ((waveId ^ vm) << 6) + lane;
        const float sgn = (waveId & vm) ? -RS2f : RS2f;
        #pragma unroll
        for (int j = 0; j < 8; ++j) {
            float4 q = p[(j << 8) + ps];
            f32x2 q_r = {q.x, q.z}, q_i = {q.y, q.w};
            vr[j] = q_r * RS2f + vr[j] * sgn;
            vi[j] = q_i * RS2f + vi[j] * sgn;
        }
    }
}

// ==================================================================
// R27 circuit: 9 exchanges (init-fold only). Plain launch_bounds(256).
// ==================================================================
__global__ __launch_bounds__(256) void circuit_red(const float* __restrict__ P,
                                                   const float* __restrict__ xf,
                                                   const CMat* __restrict__ cmg,
                                                   const float* __restrict__ bias,
                                                   float* __restrict__ out, int SK) {
    __shared__ float xbuf[8192];         // 32 KB exchange buffer -- ONLY shared mem
    const int tid = threadIdx.x, lane = tid & 63, waveId = tid >> 6;
    const int b = blockIdx.x;
    // ---- folded reduce: com[c] = bias[c] + sum_z P[z][b][c] -> xbuf[0..511]
    {
        float2 s = ((const float2*)bias)[tid];
        for (int z = 0; z < SK; ++z) {
            float2 q = ((const float2*)(P + (size_t)z * 524288 + (size_t)b * 512))[tid];
            s.x += q.x; s.y += q.y;
        }
        ((float2*)xbuf)[tid] = s;
    }
    __syncthreads();
    f32x2 vr[8], vi[8];
    #pragma unroll
    for (int p = 0; p < 8; ++p) { vr[p] = (f32x2){0.f, 0.f}; vi[p] = (f32x2){0.f, 0.f}; }
    const float K9 = 0.044194173824159216f;   // 2^-4.5
    // ---- init WITH rot(l=0,w=0) folded in: state is separable here.
    // lo-waves hold K9*c_j, hi-waves K9*s_j for the SAME j; both c,s
    // are locally available -> rot0 is register math, no exchange.
    // Zero extra register pressure (kc/ks consumed immediately).
    {
        const CMat M0 = cmg[0];
        const bool hi = waveId & 2;
        const float Pr = hi ? M0.m10r : M0.m00r, Pi = hi ? M0.m10i : M0.m00i;
        const float Qr = hi ? M0.m11r : M0.m01r, Qi = hi ? M0.m11i : M0.m01i;
        #pragma unroll
        for (int m = 0; m < 4; ++m) {
            int j = (lane << 3) | ((waveId & 1) << 2) | m;
            int rj = (int)(__brev((unsigned)j) >> 23);
            float h = 0.5f * xbuf[rj];
            float s = __sinf(h), c = __cosf(h);
            float kc = K9 * c, ks = K9 * s;
            vr[m << 1].x = Pr * kc + Qr * ks;     // elements 0,4,8,12
            vi[m << 1].x = Pi * kc + Qi * ks;
        }
    }
    // (first exch_put's leading __syncthreads orders these reads vs overwrite)
    // ---------------- layer 0 (rot0 pre-applied) ----------------
    {
        const CMat* cl = cmg;
        { CMat M = cl[1];  rot_wire<1 >(vr, vi, xbuf, waveId, lane, M); }
        { CMat M = cl[2];  rot_wire<2 >(vr, vi, xbuf, waveId, lane, M); }
        { CMat M = cl[3];  rot_wire<3 >(vr, vi, xbuf, waveId, lane, M); }
        { CMat M = cl[4];  rot_wire<4 >(vr, vi, xbuf, waveId, lane, M); }
        { CMat M = cl[5];  rot_wire<5 >(vr, vi, xbuf, waveId, lane, M); }
        { CMat M = cl[6];  rot_wire<6 >(vr, vi, xbuf, waveId, lane, M); }
        { CMat M = cl[7];  rot_wire<7 >(vr, vi, xbuf, waveId, lane, M); }
        { CMat M = cl[8];  rot_wire<8 >(vr, vi, xbuf, waveId, lane, M); }
        { CMat M = cl[9];  rot_wire<9 >(vr, vi, xbuf, waveId, lane, M); }
        { CMat M = cl[10]; rot_wire<10>(vr, vi, xbuf, waveId, lane, M); }
        { CMat M = cl[11]; rot_wire<11>(vr, vi, xbuf, waveId, lane, M); }
        // r = 1 CNOT ring
        int j = lane;
        j ^= (j & 2)  ? 1  : 0;           // C(5,6)
        j ^= (j & 4)  ? 2  : 0;           // C(4,5)
        j ^= (j & 8)  ? 4  : 0;           // C(3,4)
        j ^= (j & 16) ? 8  : 0;           // C(2,3)
        j ^= (j & 32) ? 16 : 0;           // C(1,2)
        j ^= (waveId & 2) ? 32 : 0;       // C(0,1)
        shfl_perm(vr, vi, j);
        cnot<6,7>(vr,vi,xbuf,waveId,lane);   cnot<7,8>(vr,vi,xbuf,waveId,lane);
        cnot<8,9>(vr,vi,xbuf,waveId,lane);   cnot<9,10>(vr,vi,xbuf,waveId,lane);
        cnot<10,11>(vr,vi,xbuf,waveId,lane); cnot<11,0>(vr,vi,xbuf,waveId,lane);
    }
    // ---------------- layer 1 (full 12 rots, as verified R24) ----------------
    {
        const CMat* cl = cmg + 12;
        { CMat M = cl[0];  rot_wire<0 >(vr, vi, xbuf, waveId, lane, M); }
        { CMat M = cl[1];  rot_wire<1 >(vr, vi, xbuf, waveId, lane, M); }
        { CMat M = cl[2];  rot_wire<2 >(vr, vi, xbuf, waveId, lane, M); }
        { CMat M = cl[3];  rot_wire<3 >(vr, vi, xbuf, waveId, lane, M); }
        { CMat M = cl[4];  rot_wire<4 >(vr, vi, xbuf, waveId, lane, M); }
        { CMat M = cl[5];  rot_wire<5 >(vr, vi, xbuf, waveId, lane, M); }
        { CMat M = cl[6];  rot_wire<6 >(vr, vi, xbuf, waveId, lane, M); }
        { CMat M = cl[7];  rot_wire<7 >(vr, vi, xbuf, waveId, lane, M); }
        { CMat M = cl[8];  rot_wire<8 >(vr, vi, xbuf, waveId, lane, M); }
        { CMat M = cl[9];  rot_wire<9 >(vr, vi, xbuf, waveId, lane, M); }
        { CMat M = cl[10]; rot_wire<10>(vr, vi, xbuf, waveId, lane, M); }
        { CMat M = cl[11]; rot_wire<11>(vr, vi, xbuf, waveId, lane, M); }
        // r = 2 CNOT ring
        int j = lane;
        j ^= (j & 4)  ? 1  : 0;           // C(4,6)
        j ^= (j & 8)  ? 2  : 0;           // C(3,5)
        j ^= (j & 16) ? 4  : 0;           // C(2,4)
        j ^= (j & 32) ? 8  : 0;           // C(1,3)
        j ^= (waveId & 2) ? 16 : 0;       // C(0,2)
        shfl_perm(vr, vi, j);
        cnot<5,7>(vr,vi,xbuf,waveId,lane);   cnot<6,8>(vr,vi,xbuf,waveId,lane);
        cnot<7,9>(vr,vi,xbuf,waveId,lane);   cnot<8,10>(vr,vi,xbuf,waveId,lane);
        cnot<9,11>(vr,vi,xbuf,waveId,lane);  cnot<10,0>(vr,vi,xbuf,waveId,lane);
        cnot<11,1>(vr,vi,xbuf,waveId,lane);
    }
    h_wire<1>(vr,vi,xbuf,waveId,lane);  h_wire<2>(vr,vi,xbuf,waveId,lane);
    h_wire<3>(vr,vi,xbuf,waveId,lane);  h_wire<4>(vr,vi,xbuf,waveId,lane);
    h_wire<5>(vr,vi,xbuf,waveId,lane);  h_wire<6>(vr,vi,xbuf,waveId,lane);
    h_wire<7>(vr,vi,xbuf,waveId,lane);  h_wire<8>(vr,vi,xbuf,waveId,lane);
    h_wire<9>(vr,vi,xbuf,waveId,lane);  h_wire<10>(vr,vi,xbuf,waveId,lane);
    h_wire<11>(vr,vi,xbuf,waveId,lane);
    exch_put(xbuf, (waveId << 6) + lane, vr, vi);
    {
        const float* xrow = xf + (size_t)b * 2048;
        const float4* p = (const float4*)xbuf;
        const int ps = ((waveId ^ 2) << 6) + lane;
        const bool hi = waveId & 2;
        float acc = 0.0f;
        #pragma unroll
        for (int j = 0; j < 8; ++j) {
            float4 q = p[(j << 8) + ps];
            #pragma unroll
            for (int h = 0; h < 2; ++h) {
                const int e = 2*j + h;
                const float prr = h ? q.z : q.x;
                const float pii = h ? q.w : q.y;
                const float vre = h ? vr[j].y : vr[j].x;
                const float vie = h ? vi[j].y : vi[j].x;
                int v = (lane << 5) | ((waveId & 1) << 4) | e;
                int rv = (int)(__brev((unsigned)v) >> 21);
                float ha = 0.5f * xrow[rv];         // L1/L2-resident 8KB row
                float s = __sinf(ha), c = __cosf(ha);
                float nr = hi ? (s*prr + c*vre) : (c*vre - s*prr);
                float ni = hi ? (s*pii + c*vie) : (c*vie - s*pii);
                acc += nr*nr + ni*ni;
            }
        }
        if (!hi) acc = -acc;
        #pragma unroll
        for (int off = 32; off > 0; off >>= 1) acc += __shfl_down(acc, off, 64);
        __syncthreads();
        if (lane == 0) xbuf[waveId] = acc;
        __syncthreads();
        if (tid == 0) out[b] = xbuf[0] + xbuf[1] + xbuf[2] + xbuf[3];
    }
}

extern "C" void kernel_launch(void* const* d_in, const int* in_sizes, int n_in,
                              void* d_out, int out_size, void* d_ws, size_t ws_size,
                              hipStream_t stream) {
    const float* x    = (const float*)d_in[0];   // (1024,2048)
    const float* W    = (const float*)d_in[1];   // (512,2048)
    const float* bias = (const float*)d_in[2];   // (512,)
    const float* qp   = (const float*)d_in[3];   // (2,12,3)
    float* out = (float*)d_out;                  // (1024,)

    const size_t SLAB = 2097152;                 // 2 MB per P slab
    const size_t CMSZ = 1024;                    // CMat stash
    float* P = (float*)d_ws;

    if (ws_size >= 16 * SLAB + CMSZ) {
        CMat* cmg = (CMat*)((char*)d_ws + 16 * SLAB);
        gemm_fused<<<512, 512, 0, stream>>>(x, W, P, qp, cmg);     // 128x128, SK=16
        circuit_red<<<1024, 256, 0, stream>>>(P, x, cmg, bias, out, 16);
    } else {
        CMat* cmg = (CMat*)((char*)d_ws + SLAB);       // needs SLAB+1KB
        dim3 g(16, 16);
        gemm_f32<<<g, 256, 0, stream>>>(x, W, P, qp, cmg);
        circuit_red<<<1024, 256, 0, stream>>>(P, x, cmg, bias, out, 1);
    }
}

// Round 14
// 122.130 us; speedup vs baseline: 1.0434x; 1.0434x over previous
//
#include <hip/hip_runtime.h>
#include <hip/hip_bf16.h>
#include <math.h>

#define RS2f 0.70710678118654752f

typedef __attribute__((ext_vector_type(8))) short bf16x8;
typedef __attribute__((ext_vector_type(4))) float f32x4;
typedef __attribute__((ext_vector_type(2))) float f32x2;   // <2 x float> -> v_pk_* on gfx950

__device__ __forceinline__ float bf2f(unsigned short h) {
    return __uint_as_float(((unsigned)h) << 16);
}
// HW packed fp32x2 -> bf16x2 (v_cvt_pk_bf16_f32 on gfx950, RNE)
__device__ __forceinline__ ushort2 pk2(float a, float b) {
    union { __hip_bfloat162 h; ushort2 s; } u;
    u.h = __float22bfloat162_rn(make_float2(a, b));
    return u.s;
}

// ==================== rotation matrices ====================
struct CMat { float m00r,m00i,m01r,m01i,m10r,m10i,m11r,m11i; };

__device__ __forceinline__ CMat mk_rot(const float* __restrict__ qp, int l, int w) {
    const float* g = qp + (l * 12 + w) * 3;
    float phi = g[0], th = g[1], om = g[2];
    float st, ct, sa, ca, sb, cb;
    sincosf(0.5f * th, &st, &ct);
    sincosf(0.5f * (phi + om), &sa, &ca);
    sincosf(0.5f * (phi - om), &sb, &cb);
    CMat M;
    M.m00r =  ct * ca; M.m00i = -ct * sa;
    M.m01r = -st * cb; M.m01i = -st * sb;
    M.m10r =  st * cb; M.m10i = -st * sb;
    M.m11r =  ct * ca; M.m11i =  ct * sa;
    return M;
}

// ==================================================================
// GEMM (verified since R6): 128x128 tile, SK=16, grid 512.
// ==================================================================
__global__ __launch_bounds__(512) void gemm_fused(const float* __restrict__ A,  // 1024x2048
                                                  const float* __restrict__ B,  // 512x2048
                                                  float* __restrict__ P,
                                                  const float* __restrict__ qp,
                                                  CMat* __restrict__ cmg) {
    __shared__ short As[128 * 136];      // 34816 B
    __shared__ short Bs[128 * 136];      // 34816 B
    const int tid = threadIdx.x, lane = tid & 63, wv = tid >> 6;   // wv 0..7
    const int quad = lane >> 4, mrow = lane & 15;
    const int bid = blockIdx.x;
    if (bid == 0 && tid < 24) cmg[tid] = mk_rot(qp, tid / 12, tid % 12);
    const int zt  = bid & 15;                      // K-slice 0..15
    const int idx = bid >> 4;                      // 0..31
    const int mt  = idx & 7, nt = idx >> 3;        // 8 m-tiles x 4 n-tiles
    const int m0 = mt * 128, n0 = nt * 128;
    const int kb = zt * 128;                       // fp32 K base (2048/16)
    const int srow = tid >> 2;                     // 0..127
    const int sc = (tid & 3) * 16;                 // fp32 col group

    f32x4 acc[8];
    #pragma unroll
    for (int j = 0; j < 8; ++j) acc[j] = (f32x4){0.f, 0.f, 0.f, 0.f};

    const float* Arow = A + (size_t)(m0 + srow) * 2048 + kb + sc;
    const float* Brow = B + (size_t)(n0 + srow) * 2048 + kb + sc;

    float4 av[4], bv[4];
    #pragma unroll
    for (int i = 0; i < 4; ++i) { av[i] = *(const float4*)(Arow + 4*i);
                                  bv[i] = *(const float4*)(Brow + 4*i); }

    for (int ch = 0; ch < 2; ++ch) {               // 2 x BK=64 fp32 = 128
        __syncthreads();
        #pragma unroll
        for (int i = 0; i < 4; ++i) {
            ushort2 h0 = pk2(av[i].x, av[i].y);
            ushort2 h1 = pk2(av[i].z, av[i].w);
            ushort2 l0 = pk2(av[i].x - bf2f(h0.x), av[i].y - bf2f(h0.y));
            ushort2 l1 = pk2(av[i].z - bf2f(h1.x), av[i].w - bf2f(h1.y));
            *(ushort4*)&As[srow * 136 + sc + 4*i]      = make_ushort4(h0.x, h0.y, h1.x, h1.y);
            *(ushort4*)&As[srow * 136 + 64 + sc + 4*i] = make_ushort4(l0.x, l0.y, l1.x, l1.y);
            h0 = pk2(bv[i].x, bv[i].y);
            h1 = pk2(bv[i].z, bv[i].w);
            l0 = pk2(bv[i].x - bf2f(h0.x), bv[i].y - bf2f(h0.y));
            l1 = pk2(bv[i].z - bf2f(h1.x), bv[i].w - bf2f(h1.y));
            *(ushort4*)&Bs[srow * 136 + sc + 4*i]      = make_ushort4(h0.x, h0.y, h1.x, h1.y);
            *(ushort4*)&Bs[srow * 136 + 64 + sc + 4*i] = make_ushort4(l0.x, l0.y, l1.x, l1.y);
        }
        __syncthreads();
        if (ch + 1 < 2) {
            const int o = 64;
            #pragma unroll
            for (int i = 0; i < 4; ++i) { av[i] = *(const float4*)(Arow + o + 4*i);
                                          bv[i] = *(const float4*)(Brow + o + 4*i); }
        }
        #pragma unroll
        for (int s = 0; s < 4; ++s) {              // K-segments: 2 hi, 2 lo
            const int off = s * 32 + quad * 8;
            bf16x8 af = *(const bf16x8*)&As[(wv * 16 + mrow) * 136 + off];
            #pragma unroll
            for (int j = 0; j < 8; ++j) {
                bf16x8 bf = *(const bf16x8*)&Bs[(j * 16 + mrow) * 136 + off];
                acc[j] = __builtin_amdgcn_mfma_f32_16x16x32_bf16(af, bf, acc[j], 0, 0, 0);
            }
        }
    }
    // C/D layout: col = lane&15, row = quad*4 + r
    float* Pz = P + (size_t)zt * 524288;
    #pragma unroll
    for (int j = 0; j < 8; ++j)
        #pragma unroll
        for (int r = 0; r < 4; ++r)
            Pz[(m0 + wv * 16 + quad * 4 + r) * 512 + n0 + j * 16 + mrow] = acc[j][r];
}

// ==================================================================
// Fallback fp32 GEMM (tiny ws): raw product to P; circuit adds bias.
// ==================================================================
__global__ __launch_bounds__(256) void gemm_f32(const float* __restrict__ A,
                                                const float* __restrict__ W,
                                                float* __restrict__ C,
                                                const float* __restrict__ qp,
                                                CMat* __restrict__ cmg) {
    __shared__ float Asf[64][33];
    __shared__ float Bsf[32][33];
    const int tid = threadIdx.x;
    if (blockIdx.x == 0 && blockIdx.y == 0 && tid < 24)
        cmg[tid] = mk_rot(qp, tid / 12, tid % 12);
    const int m0 = blockIdx.x * 64;
    const int n0 = blockIdx.y * 32;
    const int tm = tid >> 4, tn = tid & 15;
    float acc[4][2] = {};
    for (int k0 = 0; k0 < 2048; k0 += 32) {
        #pragma unroll
        for (int i = 0; i < 8; ++i) {
            int idx = tid + i * 256;
            Asf[idx >> 5][idx & 31] = A[(m0 + (idx >> 5)) * 2048 + k0 + (idx & 31)];
        }
        #pragma unroll
        for (int i = 0; i < 4; ++i) {
            int idx = tid + i * 256;
            Bsf[idx >> 5][idx & 31] = W[(n0 + (idx >> 5)) * 2048 + k0 + (idx & 31)];
        }
        __syncthreads();
        #pragma unroll
        for (int kk = 0; kk < 32; ++kk) {
            float a0 = Asf[tm*4+0][kk], a1 = Asf[tm*4+1][kk];
            float a2 = Asf[tm*4+2][kk], a3 = Asf[tm*4+3][kk];
            float b0 = Bsf[tn*2+0][kk], b1 = Bsf[tn*2+1][kk];
            acc[0][0] += a0*b0; acc[0][1] += a0*b1;
            acc[1][0] += a1*b0; acc[1][1] += a1*b1;
            acc[2][0] += a2*b0; acc[2][1] += a2*b1;
            acc[3][0] += a3*b0; acc[3][1] += a3*b1;
        }
        __syncthreads();
    }
    #pragma unroll
    for (int r = 0; r < 4; ++r)
        #pragma unroll
        for (int c = 0; c < 2; ++c)
            C[(m0 + tm*4 + r) * 512 + n0 + tn*2 + c] = acc[r][c];
}

// ==================== circuit helpers ====================
// R24 FINAL (verified 122.7us total in R8 and R11; best of session).
// State held as f32x2 pairs (wire-11 axis) -- packed resting
// representation; DPP for xor-masks 1/2/8; ds path otherwise.
// NOTE (session lessons): do NOT add a min-waves launch_bounds arg
// (R3/R5: forced spill; R9/R10: container death) and do NOT fuse
// exchanges (R12/R13: regalloc perturbation costs more occupancy
// than the saved exchange is worth -- 54.0 -> 57.4/60.2us).
template<int W> struct WI {
    static constexpr int kind = (W == 0 || W == 7) ? 2 : ((W >= 1 && W <= 6) ? 1 : 0);
    static constexpr int eb   = (W >= 8) ? (11 - W) : 0;
    static constexpr int lm   = (W >= 1 && W <= 6) ? (1 << (6 - W)) : 0;
    static constexpr int vm   = (W == 0) ? 2 : ((W == 7) ? 1 : 0);
};

// xor-shuffle: DPP for masks 1,2,8 (exact lane permutations, all lanes
// active at every callsite); ds path otherwise.
template<int M>
__device__ __forceinline__ float xshfl(float v) {
    if constexpr (M == 1) {        // quad_perm [1,0,3,2]
        return __int_as_float(__builtin_amdgcn_update_dpp(
            __float_as_int(v), __float_as_int(v), 177, 0xf, 0xf, false));
    } else if constexpr (M == 2) { // quad_perm [2,3,0,1]
        return __int_as_float(__builtin_amdgcn_update_dpp(
            __float_as_int(v), __float_as_int(v), 78, 0xf, 0xf, false));
    } else if constexpr (M == 8) { // row_ror:8 (16-lane row; +8 mod 16 == xor 8)
        return __int_as_float(__builtin_amdgcn_update_dpp(
            __float_as_int(v), __float_as_int(v), 0x128, 0xf, 0xf, false));
    } else {
        return __shfl_xor(v, M, 64);
    }
}

__device__ __forceinline__ float getv(const f32x2 a[8], int e) {
    return (e & 1) ? a[e >> 1].y : a[e >> 1].x;
}
__device__ __forceinline__ void setv(f32x2 a[8], int e, float v) {
    if (e & 1) a[e >> 1].y = v; else a[e >> 1].x = v;
}

__device__ __forceinline__ void exch_put(float* xbuf, int slot,
                                         const f32x2 vr[8], const f32x2 vi[8]) {
    __syncthreads();
    float4* p = (float4*)xbuf;
    #pragma unroll
    for (int j = 0; j < 8; ++j)
        p[(j << 8) + slot] = make_float4(vr[j].x, vi[j].x, vr[j].y, vi[j].y);
    __syncthreads();
}

__device__ __forceinline__ void shfl_perm(f32x2 vr[8], f32x2 vi[8], int src) {
    #pragma unroll
    for (int p = 0; p < 8; ++p) {
        vr[p].x = __shfl(vr[p].x, src, 64); vr[p].y = __shfl(vr[p].y, src, 64);
        vi[p].x = __shfl(vi[p].x, src, 64); vi[p].y = __shfl(vi[p].y, src, 64);
    }
}

template<int EB>
__device__ __forceinline__ void rot_local(f32x2 vr[8], f32x2 vi[8], const CMat& M) {
    if constexpr (EB == 0) {
        #pragma unroll
        for (int p = 0; p < 8; ++p) {
            float x0r = vr[p].x, x0i = vi[p].x, x1r = vr[p].y, x1i = vi[p].y;
            vr[p].x = M.m00r*x0r - M.m00i*x0i + M.m01r*x1r - M.m01i*x1i;
            vi[p].x = M.m00r*x0i + M.m00i*x0r + M.m01r*x1i + M.m01i*x1r;
            vr[p].y = M.m10r*x0r - M.m10i*x0i + M.m11r*x1r - M.m11i*x1i;
            vi[p].y = M.m10r*x0i + M.m10i*x0r + M.m11r*x1i + M.m11i*x1r;
        }
    } else {
        constexpr int pb = 1 << (EB - 1);
        #pragma unroll
        for (int p = 0; p < 8; ++p) if (!(p & pb)) {
            const int p1 = p | pb;
            f32x2 x0r = vr[p], x0i = vi[p], x1r = vr[p1], x1i = vi[p1];
            vr[p]  = M.m00r*x0r - M.m00i*x0i + M.m01r*x1r - M.m01i*x1i;
            vi[p]  = M.m00r*x0i + M.m00i*x0r + M.m01r*x1i + M.m01i*x1r;
            vr[p1] = M.m10r*x0r - M.m10i*x0i + M.m11r*x1r - M.m11i*x1i;
            vi[p1] = M.m10r*x0i + M.m10i*x0r + M.m11r*x1i + M.m11i*x1r;
        }
    }
}

template<int LM>
__device__ __forceinline__ void rot_lane(f32x2 vr[8], f32x2 vi[8], int lane, const CMat& M) {
    const bool hi = lane & LM;
    const float Ar = hi ? M.m11r : M.m00r, Ai = hi ? M.m11i : M.m00i;
    const float Br = hi ? M.m10r : M.m01r, Bi = hi ? M.m10i : M.m01i;
    #pragma unroll
    for (int p = 0; p < 8; ++p) {
        f32x2 p_r = { xshfl<LM>(vr[p].x), xshfl<LM>(vr[p].y) };
        f32x2 p_i = { xshfl<LM>(vi[p].x), xshfl<LM>(vi[p].y) };
        f32x2 o_r = vr[p], o_i = vi[p];
        vr[p] = Ar*o_r - Ai*o_i + Br*p_r - Bi*p_i;
        vi[p] = Ar*o_i + Ai*o_r + Br*p_i + Bi*p_r;
    }
}

template<int VM>
__device__ __forceinline__ void rot_wave(f32x2 vr[8], f32x2 vi[8], float* xbuf,
                                         int waveId, int lane, const CMat& M) {
    exch_put(xbuf, (waveId << 6) + lane, vr, vi);
    const float4* p = (const float4*)xbuf;
    const int ps = ((waveId ^ VM) << 6) + lane;
    const bool hi = waveId & VM;
    const float Ar = hi ? M.m11r : M.m00r, Ai = hi ? M.m11i : M.m00i;
    const float Br = hi ? M.m10r : M.m01r, Bi = hi ? M.m10i : M.m01i;
    #pragma unroll
    for (int j = 0; j < 8; ++j) {
        float4 q = p[(j << 8) + ps];
        f32x2 q_r = {q.x, q.z}, q_i = {q.y, q.w};
        f32x2 o_r = vr[j], o_i = vi[j];
        vr[j] = Ar*o_r - Ai*o_i + Br*q_r - Bi*q_i;
        vi[j] = Ar*o_i + Ai*o_r + Br*q_i + Bi*q_r;
    }
}

template<int W>
__device__ __forceinline__ void rot_wire(f32x2 vr[8], f32x2 vi[8], float* xbuf,
                                         int waveId, int lane, const CMat& M) {
    if constexpr (WI<W>::kind == 0)      rot_local<WI<W>::eb>(vr, vi, M);
    else if constexpr (WI<W>::kind == 1) rot_lane<WI<W>::lm>(vr, vi, lane, M);
    else                                 rot_wave<WI<W>::vm>(vr, vi, xbuf, waveId, lane, M);
}

template<int C, int T>
__device__ __forceinline__ void cnot(f32x2 vr[8], f32x2 vi[8], float* xbuf,
                                     int waveId, int lane) {
    constexpr int ck = WI<C>::kind, tk = WI<T>::kind;
    if constexpr (ck == 0 && tk == 0) {
        constexpr int cb = 1 << WI<C>::eb, tb = 1 << WI<T>::eb;
        #pragma unroll
        for (int e = 0; e < 16; ++e) if ((e & cb) && !(e & tb)) {
            const int e1 = e | tb;
            float t = getv(vr, e); setv(vr, e, getv(vr, e1)); setv(vr, e1, t);
            t = getv(vi, e); setv(vi, e, getv(vi, e1)); setv(vi, e1, t);
        }
    } else if constexpr (ck == 0 && tk == 1) {
        constexpr int cb = 1 << WI<C>::eb, tm = WI<T>::lm;
        #pragma unroll
        for (int e = 0; e < 16; ++e) if (e & cb) {
            setv(vr, e, xshfl<tm>(getv(vr, e)));
            setv(vi, e, xshfl<tm>(getv(vi, e)));
        }
    } else if constexpr (ck == 0 && tk == 2) {
        constexpr int cb = 1 << WI<C>::eb, vm = WI<T>::vm;
        exch_put(xbuf, (waveId << 6) + lane, vr, vi);
        const float4* p = (const float4*)xbuf;
        const int ps = ((waveId ^ vm) << 6) + lane;
        #pragma unroll
        for (int j = 0; j < 8; ++j) {
            if ((((2*j) & cb) != 0) || (((2*j+1) & cb) != 0)) {
                float4 q = p[(j << 8) + ps];
                if (((2*j) & cb) != 0)   { vr[j].x = q.x; vi[j].x = q.y; }
                if (((2*j+1) & cb) != 0) { vr[j].y = q.z; vi[j].y = q.w; }
            }
        }
    } else if constexpr (ck == 1 && tk == 0) {
        constexpr int cm = WI<C>::lm, tb = 1 << WI<T>::eb;
        const bool cc = lane & cm;
        #pragma unroll
        for (int e = 0; e < 16; ++e) if (!(e & tb)) {
            const int e1 = e | tb;
            float a = getv(vr, e), bb = getv(vr, e1);
            setv(vr, e, cc ? bb : a); setv(vr, e1, cc ? a : bb);
            a = getv(vi, e); bb = getv(vi, e1);
            setv(vi, e, cc ? bb : a); setv(vi, e1, cc ? a : bb);
        }
    } else if constexpr (ck == 1 && tk == 1) {
        constexpr int cm = WI<C>::lm, tm = WI<T>::lm;
        const int src = (lane & cm) ? (lane ^ tm) : lane;
        shfl_perm(vr, vi, src);
    } else if constexpr (ck == 1 && tk == 2) {
        constexpr int cm = WI<C>::lm, vm = WI<T>::vm;
        exch_put(xbuf, (waveId << 6) + lane, vr, vi);
        const float4* p = (const float4*)xbuf;
        const int ps = ((waveId ^ vm) << 6) + lane;
        const bool take = lane & cm;
        #pragma unroll
        for (int j = 0; j < 8; ++j) {
            float4 q = p[(j << 8) + ps];
            vr[j].x = take ? q.x : vr[j].x;   vi[j].x = take ? q.y : vi[j].x;
            vr[j].y = take ? q.z : vr[j].y;   vi[j].y = take ? q.w : vi[j].y;
        }
    } else if constexpr (ck == 2 && tk == 0) {
        constexpr int vm = WI<C>::vm, tb = 1 << WI<T>::eb;
        if (waveId & vm) {
            #pragma unroll
            for (int e = 0; e < 16; ++e) if (!(e & tb)) {
                const int e1 = e | tb;
                float t = getv(vr, e); setv(vr, e, getv(vr, e1)); setv(vr, e1, t);
                t = getv(vi, e); setv(vi, e, getv(vi, e1)); setv(vi, e1, t);
            }
        }
    } else {
        constexpr int vm = WI<C>::vm, tm = WI<T>::lm;
        if (waveId & vm) {
            #pragma unroll
            for (int e = 0; e < 16; ++e) {
                setv(vr, e, __shfl_xor(getv(vr, e), tm, 64));
                setv(vi, e, __shfl_xor(getv(vi, e), tm, 64));
            }
        }
    }
}

template<int W>
__device__ __forceinline__ void h_wire(f32x2 vr[8], f32x2 vi[8], float* xbuf,
                                       int waveId, int lane) {
    if constexpr (WI<W>::kind == 0) {
        if constexpr (WI<W>::eb == 0) {
            #pragma unroll
            for (int p = 0; p < 8; ++p) {
                float x0 = vr[p].x, x1 = vr[p].y;
                vr[p].x = (x0 + x1) * RS2f; vr[p].y = (x0 - x1) * RS2f;
                x0 = vi[p].x; x1 = vi[p].y;
                vi[p].x = (x0 + x1) * RS2f; vi[p].y = (x0 - x1) * RS2f;
            }
        } else {
            constexpr int pb = 1 << (WI<W>::eb - 1);
            #pragma unroll
            for (int p = 0; p < 8; ++p) if (!(p & pb)) {
                const int p1 = p | pb;
                f32x2 a = vr[p], b = vr[p1];
                vr[p] = (a + b) * RS2f; vr[p1] = (a - b) * RS2f;
                a = vi[p]; b = vi[p1];
                vi[p] = (a + b) * RS2f; vi[p1] = (a - b) * RS2f;
            }
        }
    } else if constexpr (WI<W>::kind == 1) {
        constexpr int m = WI<W>::lm;
        const float sgn = (lane & m) ? -RS2f : RS2f;
        #pragma unroll
        for (int p = 0; p < 8; ++p) {
            f32x2 p_r = { xshfl<m>(vr[p].x), xshfl<m>(vr[p].y) };
            f32x2 p_i = { xshfl<m>(vi[p].x), xshfl<m>(vi[p].y) };
            vr[p] = p_r * RS2f + vr[p] * sgn;
            vi[p] = p_i * RS2f + vi[p] * sgn;
        }
    } else {
        constexpr int vm = WI<W>::vm;
        exch_put(xbuf, (waveId << 6) + lane, vr, vi);
        const float4* p = (const float4*)xbuf;
        const int ps = ((waveId ^ vm) << 6) + lane;
        const float sgn = (waveId & vm) ? -RS2f : RS2f;
        #pragma unroll
        for (int j = 0; j < 8; ++j) {
            float4 q = p[(j << 8) + ps];
            f32x2 q_r = {q.x, q.z}, q_i = {q.y, q.w};
            vr[j] = q_r * RS2f + vr[j] * sgn;
            vi[j] = q_i * RS2f + vi[j] * sgn;
        }
    }
}

// ==================================================================
// R24 circuit FINAL (verified 54.0us in R8/R11): f32x2-resident state
// + DPP shuffles. Plain launch_bounds(256).
// ==================================================================
__global__ __launch_bounds__(256) void circuit_red(const float* __restrict__ P,
                                                   const float* __restrict__ xf,
                                                   const CMat* __restrict__ cmg,
                                                   const float* __restrict__ bias,
                                                   float* __restrict__ out, int SK) {
    __shared__ float xbuf[8192];         // 32 KB exchange buffer -- ONLY shared mem
    const int tid = threadIdx.x, lane = tid & 63, waveId = tid >> 6;
    const int b = blockIdx.x;
    // ---- folded reduce: com[c] = bias[c] + sum_z P[z][b][c] -> xbuf[0..511]
    {
        float2 s = ((const float2*)bias)[tid];
        for (int z = 0; z < SK; ++z) {
            float2 q = ((const float2*)(P + (size_t)z * 524288 + (size_t)b * 512))[tid];
            s.x += q.x; s.y += q.y;
        }
        ((float2*)xbuf)[tid] = s;
    }
    __syncthreads();
    f32x2 vr[8], vi[8];
    #pragma unroll
    for (int p = 0; p < 8; ++p) { vr[p] = (f32x2){0.f, 0.f}; vi[p] = (f32x2){0.f, 0.f}; }
    const float K9 = 0.044194173824159216f;   // 2^-4.5
    #pragma unroll
    for (int m = 0; m < 4; ++m) {
        int j = (lane << 3) | ((waveId & 1) << 2) | m;
        int rj = (int)(__brev((unsigned)j) >> 23);
        float h = 0.5f * xbuf[rj];
        float s = __sinf(h), c = __cosf(h);
        vr[(m << 2) >> 1].x = K9 * ((waveId & 2) ? s : c);   // elements 0,4,8,12
    }
    // (first exch_put's leading __syncthreads orders these reads vs overwrite)
    #pragma unroll 1
    for (int l = 0; l < 2; ++l) {
        const CMat* cl = cmg + l * 12;
        { CMat M = cl[0];  rot_wire<0 >(vr, vi, xbuf, waveId, lane, M); }
        { CMat M = cl[1];  rot_wire<1 >(vr, vi, xbuf, waveId, lane, M); }
        { CMat M = cl[2];  rot_wire<2 >(vr, vi, xbuf, waveId, lane, M); }
        { CMat M = cl[3];  rot_wire<3 >(vr, vi, xbuf, waveId, lane, M); }
        { CMat M = cl[4];  rot_wire<4 >(vr, vi, xbuf, waveId, lane, M); }
        { CMat M = cl[5];  rot_wire<5 >(vr, vi, xbuf, waveId, lane, M); }
        { CMat M = cl[6];  rot_wire<6 >(vr, vi, xbuf, waveId, lane, M); }
        { CMat M = cl[7];  rot_wire<7 >(vr, vi, xbuf, waveId, lane, M); }
        { CMat M = cl[8];  rot_wire<8 >(vr, vi, xbuf, waveId, lane, M); }
        { CMat M = cl[9];  rot_wire<9 >(vr, vi, xbuf, waveId, lane, M); }
        { CMat M = cl[10]; rot_wire<10>(vr, vi, xbuf, waveId, lane, M); }
        { CMat M = cl[11]; rot_wire<11>(vr, vi, xbuf, waveId, lane, M); }
        if (l == 0) {                 // r = 1
            int j = lane;
            j ^= (j & 2)  ? 1  : 0;           // C(5,6)
            j ^= (j & 4)  ? 2  : 0;           // C(4,5)
            j ^= (j & 8)  ? 4  : 0;           // C(3,4)
            j ^= (j & 16) ? 8  : 0;           // C(2,3)
            j ^= (j & 32) ? 16 : 0;           // C(1,2)
            j ^= (waveId & 2) ? 32 : 0;       // C(0,1)
            shfl_perm(vr, vi, j);
            cnot<6,7>(vr,vi,xbuf,waveId,lane);   cnot<7,8>(vr,vi,xbuf,waveId,lane);
            cnot<8,9>(vr,vi,xbuf,waveId,lane);   cnot<9,10>(vr,vi,xbuf,waveId,lane);
            cnot<10,11>(vr,vi,xbuf,waveId,lane); cnot<11,0>(vr,vi,xbuf,waveId,lane);
        } else {                      // r = 2
            int j = lane;
            j ^= (j & 4)  ? 1  : 0;           // C(4,6)
            j ^= (j & 8)  ? 2  : 0;           // C(3,5)
            j ^= (j & 16) ? 4  : 0;           // C(2,4)
            j ^= (j & 32) ? 8  : 0;           // C(1,3)
            j ^= (waveId & 2) ? 16 : 0;       // C(0,2)
            shfl_perm(vr, vi, j);
            cnot<5,7>(vr,vi,xbuf,waveId,lane);   cnot<6,8>(vr,vi,xbuf,waveId,lane);
            cnot<7,9>(vr,vi,xbuf,waveId,lane);   cnot<8,10>(vr,vi,xbuf,waveId,lane);
            cnot<9,11>(vr,vi,xbuf,waveId,lane);  cnot<10,0>(vr,vi,xbuf,waveId,lane);
            cnot<11,1>(vr,vi,xbuf,waveId,lane);
        }
    }
    h_wire<1>(vr,vi,xbuf,waveId,lane);  h_wire<2>(vr,vi,xbuf,waveId,lane);
    h_wire<3>(vr,vi,xbuf,waveId,lane);  h_wire<4>(vr,vi,xbuf,waveId,lane);
    h_wire<5>(vr,vi,xbuf,waveId,lane);  h_wire<6>(vr,vi,xbuf,waveId,lane);
    h_wire<7>(vr,vi,xbuf,waveId,lane);  h_wire<8>(vr,vi,xbuf,waveId,lane);
    h_wire<9>(vr,vi,xbuf,waveId,lane);  h_wire<10>(vr,vi,xbuf,waveId,lane);
    h_wire<11>(vr,vi,xbuf,waveId,lane);
    exch_put(xbuf, (waveId << 6) + lane, vr, vi);
    {
        const float* xrow = xf + (size_t)b * 2048;
        const float4* p = (const float4*)xbuf;
        const int ps = ((waveId ^ 2) << 6) + lane;
        const bool hi = waveId & 2;
        float acc = 0.0f;
        #pragma unroll
        for (int j = 0; j < 8; ++j) {
            float4 q = p[(j << 8) + ps];
            #pragma unroll
            for (int h = 0; h < 2; ++h) {
                const int e = 2*j + h;
                const float prr = h ? q.z : q.x;
                const float pii = h ? q.w : q.y;
                const float vre = h ? vr[j].y : vr[j].x;
                const float vie = h ? vi[j].y : vi[j].x;
                int v = (lane << 5) | ((waveId & 1) << 4) | e;
                int rv = (int)(__brev((unsigned)v) >> 21);
                float ha = 0.5f * xrow[rv];         // L1/L2-resident 8KB row
                float s = __sinf(ha), c = __cosf(ha);
                float nr = hi ? (s*prr + c*vre) : (c*vre - s*prr);
                float ni = hi ? (s*pii + c*vie) : (c*vie - s*pii);
                acc += nr*nr + ni*ni;
            }
        }
        if (!hi) acc = -acc;
        #pragma unroll
        for (int off = 32; off > 0; off >>= 1) acc += __shfl_down(acc, off, 64);
        __syncthreads();
        if (lane == 0) xbuf[waveId] = acc;
        __syncthreads();
        if (tid == 0) out[b] = xbuf[0] + xbuf[1] + xbuf[2] + xbuf[3];
    }
}

extern "C" void kernel_launch(void* const* d_in, const int* in_sizes, int n_in,
                              void* d_out, int out_size, void* d_ws, size_t ws_size,
                              hipStream_t stream) {
    const float* x    = (const float*)d_in[0];   // (1024,2048)
    const float* W    = (const float*)d_in[1];   // (512,2048)
    const float* bias = (const float*)d_in[2];   // (512,)
    const float* qp   = (const float*)d_in[3];   // (2,12,3)
    float* out = (float*)d_out;                  // (1024,)

    const size_t SLAB = 2097152;                 // 2 MB per P slab
    const size_t CMSZ = 1024;                    // CMat stash
    float* P = (float*)d_ws;

    if (ws_size >= 16 * SLAB + CMSZ) {
        CMat* cmg = (CMat*)((char*)d_ws + 16 * SLAB);
        gemm_fused<<<512, 512, 0, stream>>>(x, W, P, qp, cmg);     // 128x128, SK=16
        circuit_red<<<1024, 256, 0, stream>>>(P, x, cmg, bias, out, 16);
    } else {
        CMat* cmg = (CMat*)((char*)d_ws + SLAB);       // needs SLAB+1KB
        dim3 g(16, 16);
        gemm_f32<<<g, 256, 0, stream>>>(x, W, P, qp, cmg);
        circuit_red<<<1024, 256, 0, stream>>>(P, x, cmg, bias, out, 1);
    }
}